// Round 6
// baseline (153.446 us; speedup 1.0000x reference)
//
#include <hip/hip_runtime.h>
#include <math.h>

#define NTOK 8192
#define NEMB 8192
#define DIM  256

typedef _Float16 f16x8 __attribute__((ext_vector_type(8)));   // 4 VGPRs
typedef _Float16 f16x4 __attribute__((ext_vector_type(4)));
typedef float    f32x4 __attribute__((ext_vector_type(4)));

// ---------------------------------------------------------------------------
// Kernel A: cast X and C to fp16 (RNE); fused exact fp32 ||c||^2 and ||x||^2
// (each wave covers exactly one 256-elem row). C-branch blocks x<8 zero
// counts; X-branch blocks x<8 init keys to u64-max; C-branch block x==8
// zeroes the done[64]+fin completion counters (required every launch for
// the fused last-block gather/finalize to be replay-safe).
__global__ __launch_bounds__(256) void convert_kernel(
        const float* __restrict__ X, const float* __restrict__ C,
        _Float16* __restrict__ Xh, _Float16* __restrict__ Ch,
        float* __restrict__ cnorm, float* __restrict__ xnorm,
        unsigned long long* __restrict__ keys, int* __restrict__ counts,
        unsigned* __restrict__ ctrl) {                 // done[64] + fin
    const bool isC = (blockIdx.y != 0);
    if (isC && blockIdx.x < 8) {
        ((int4*)counts)[blockIdx.x * 256 + threadIdx.x] = make_int4(0, 0, 0, 0);
    }
    if (isC && blockIdx.x == 8 && threadIdx.x < 65) {
        ctrl[threadIdx.x] = 0;
    }
    if (!isC && blockIdx.x < 8) {
        int4 ff = make_int4(-1, -1, -1, -1);
        ((int4*)keys)[blockIdx.x * 512 + threadIdx.x * 2]     = ff;
        ((int4*)keys)[blockIdx.x * 512 + threadIdx.x * 2 + 1] = ff;
    }
    const float* src = isC ? C : X;
    _Float16* dst = isC ? Ch : Xh;
    size_t t = (size_t)blockIdx.x * 256 + threadIdx.x;   // one float4 per thread
    float4 x = *(const float4*)&src[t * 4];
    f16x4 h;
    h[0] = (_Float16)x.x; h[1] = (_Float16)x.y;
    h[2] = (_Float16)x.z; h[3] = (_Float16)x.w;
    *(f16x4*)&dst[t * 4] = h;
    float s = x.x * x.x + x.y * x.y + x.z * x.z + x.w * x.w;
    #pragma unroll
    for (int off = 32; off >= 1; off >>= 1) s += __shfl_xor(s, off);
    if ((threadIdx.x & 63) == 0) {
        if (isC) cnorm[t >> 6] = s; else xnorm[t >> 6] = s;
    }
}

// ---------------------------------------------------------------------------
// K32-chunk staging, 256x128 block tile (A=256 codes, B=128 tokens),
// 512 threads / 8 waves of 64x64 each (proven R5 structure, untouched).
// Swizzle s(row) = (row + (row>>2)) & 3 keeps frag ds_read_b128 at 2-way.
__device__ __forceinline__ int swz(int row) { return (row + (row >> 2)) & 3; }

template<int N>
__device__ __forceinline__ void wait_vmcnt() {
    asm volatile("s_waitcnt vmcnt(%0)" :: "n"(N) : "memory");
}

// One K32 chunk: A = 1024 granules, B = 512 granules of 16B. With 512
// threads: 2 A + 1 B = 3 gload_lds/thread — vmcnt(3) relies on this.
__device__ __forceinline__ void stage_k32(
        const _Float16* __restrict__ Ag, const _Float16* __restrict__ Bg,
        _Float16* bufA, _Float16* bufB, int t) {
    #pragma unroll
    for (int c = 0; c < 2; ++c) {
        int gr  = c * 512 + t;
        int row = gr >> 2;
        int kg  = (gr & 3) ^ swz(row);
        __builtin_amdgcn_global_load_lds(
            (const __attribute__((address_space(1))) void*)(Ag + (size_t)row * DIM + kg * 8),
            (__attribute__((address_space(3))) void*)(bufA + (size_t)gr * 8), 16, 0, 0);
    }
    {
        int gr  = t;
        int row = gr >> 2;
        int kg  = (gr & 3) ^ swz(row);
        __builtin_amdgcn_global_load_lds(
            (const __attribute__((address_space(1))) void*)(Bg + (size_t)row * DIM + kg * 8),
            (__attribute__((address_space(3))) void*)(bufB + (size_t)gr * 8), 16, 0, 0);
    }
}

// 64x64 wave tile: 8 ds_read_b128 feed 16 MFMAs; acc = 64 VGPRs so
// 4 waves/SIMD fit (the R5 occupancy win).
__device__ __forceinline__ void compute_k32(
        const _Float16* Abuf, const _Float16* Bbuf, f32x4 (&acc)[4][4],
        int wm, int wn, int lrow, int g) {
    f16x8 af[4], bf_[4];
    #pragma unroll
    for (int i = 0; i < 4; ++i) {
        int row = wm + i * 16 + lrow;
        af[i] = *(const f16x8*)&Abuf[(row * 4 + (g ^ swz(row))) * 8];
    }
    #pragma unroll
    for (int j = 0; j < 4; ++j) {
        int row = wn + j * 16 + lrow;
        bf_[j] = *(const f16x8*)&Bbuf[(row * 4 + (g ^ swz(row))) * 8];
    }
    __builtin_amdgcn_s_setprio(1);
    #pragma unroll
    for (int i = 0; i < 4; ++i)
        #pragma unroll
        for (int j = 0; j < 4; ++j)
            acc[i][j] = __builtin_amdgcn_mfma_f32_16x16x32_f16(
                af[i], bf_[j], acc[i][j], 0, 0, 0);
    __builtin_amdgcn_s_setprio(0);
}

// ---------------------------------------------------------------------------
// Kernel B (FUSED): fp16 distance GEMM + argmin (R5 structure, unchanged),
// then last-block-per-token-column does the gather/histogram/loss-partial,
// and the globally-last gather block does the entropy finalize. This
// removes 2 kernel launches (+their stream gaps, the suspected ~71 us
// residue). Synchronization: atomicMin(keys) are drained at the block's
// final __syncthreads (vmcnt0); release = __threadfence + atomicAdd(done);
// the 32nd arriver acquires via __threadfence then reads keys. Same
// release/acquire chain for counts/psum -> fin -> finalize. All atomics
// commutative; ctrl counters re-zeroed each launch by convert => replay-safe.
__global__ __launch_bounds__(512, 4) void mfma_argmin_kernel(
        const _Float16* __restrict__ Xh, const _Float16* __restrict__ Ch,
        const float* __restrict__ cnorm,
        unsigned long long* __restrict__ keys,
        const float* __restrict__ C, const float* __restrict__ xnorm,
        int* __restrict__ counts, float* __restrict__ out,
        float* __restrict__ psum, unsigned* __restrict__ ctrl) {
    __shared__ __align__(16) _Float16 lds[36864];   // 72 KB
    _Float16* const ldsB = lds + 24576;             // B ring base (48 KB in)
    __shared__ int   sidx[128];
    __shared__ float spart[8];
    __shared__ double sdd[8];
    __shared__ float  sls[8];
    __shared__ int sflag;

    const int t = threadIdx.x;                      // 0..511
    const int wid = t >> 6, lane = t & 63;
    const int tb0 = blockIdx.x * 128;   // token block
    const int cb0 = blockIdx.y * 256;   // code block
    const int wm = (wid >> 1) * 64;     // wave's code offset (0/64/128/192)
    const int wn = (wid & 1) * 64;      // wave's token offset (0/64)
    const int lrow = lane & 15;
    const int g = lane >> 4;            // quad

    f32x4 acc[4][4];                    // [tm=codes][tn=tokens] = 64 VGPRs
    #pragma unroll
    for (int a = 0; a < 4; ++a)
        #pragma unroll
        for (int b = 0; b < 4; ++b) acc[a][b] = (f32x4)0.0f;

    const _Float16* Ag = Ch + (size_t)cb0 * DIM;   // codes
    const _Float16* Bg = Xh + (size_t)tb0 * DIM;   // tokens

    stage_k32(Ag,      Bg,      lds,        ldsB,        t);  // S(0)
    stage_k32(Ag + 32, Bg + 32, lds + 8192, ldsB + 4096, t);  // S(1)

    // Phase P: vmcnt(3) -> S(P) landed (S(P+1)'s 3 in flight); barrier ->
    // all waves' S(P) visible AND all done with compute(P-1) (last reader
    // of ring slot (P+2)%3); stage S(P+2); compute(P). sched_barrier(0)
    // pins ds_reads below the barrier (rule-#18 hazard class).
#define PHASE(P, WAITN)                                                       \
    do {                                                                      \
        wait_vmcnt<WAITN>();                                                  \
        __builtin_amdgcn_s_barrier();                                         \
        __builtin_amdgcn_sched_barrier(0);                                    \
        if ((P) + 2 < 8)                                                      \
            stage_k32(Ag + ((P) + 2) * 32, Bg + ((P) + 2) * 32,               \
                      lds + (((P) + 2) % 3) * 8192,                           \
                      ldsB + (((P) + 2) % 3) * 4096, t);                      \
        compute_k32(lds + ((P) % 3) * 8192, ldsB + ((P) % 3) * 4096,          \
                    acc, wm, wn, lrow, g);                                    \
        __builtin_amdgcn_sched_barrier(0);                                    \
    } while (0)

    PHASE(0, 3); PHASE(1, 3); PHASE(2, 3); PHASE(3, 3);
    PHASE(4, 3); PHASE(5, 3); PHASE(6, 3); PHASE(7, 0);
#undef PHASE

    // ---- epilogue: d = ||c||^2 - 2 c.x ; argmin over this block's 256 codes
    float cn[16];
    #pragma unroll
    for (int tm = 0; tm < 4; ++tm)
        #pragma unroll
        for (int reg = 0; reg < 4; ++reg)
            cn[tm * 4 + reg] = cnorm[cb0 + wm + tm * 16 + g * 4 + reg];

    float* cmb_v = (float*)lds;                    // [128][4]
    int*   cmb_i = (int*)((float*)lds + 512);      // [128][4]

    #pragma unroll
    for (int tn = 0; tn < 4; ++tn) {
        float bv = 1e30f; int bi = 0x7fffffff;
        #pragma unroll
        for (int tm = 0; tm < 4; ++tm) {
            #pragma unroll
            for (int reg = 0; reg < 4; ++reg) {
                float d = fmaf(-2.0f, acc[tm][tn][reg], cn[tm * 4 + reg]);
                int code = cb0 + wm + tm * 16 + g * 4 + reg;  // ascending -> strict <
                if (d < bv) { bv = d; bi = code; }
            }
        }
        #pragma unroll
        for (int off = 16; off <= 32; off <<= 1) {  // reduce over the 4 quads
            float ov = __shfl_xor(bv, off);
            int   oi = __shfl_xor(bi, off);
            if (ov < bv || (ov == bv && oi < bi)) { bv = ov; bi = oi; }
        }
        if (g == 0) {
            int tl = wn + tn * 16 + lrow;           // token-local 0..127
            cmb_v[tl * 4 + (wid >> 1)] = bv;
            cmb_i[tl * 4 + (wid >> 1)] = bi;
        }
    }
    __syncthreads();
    if (t < 128) {
        float bv = cmb_v[t * 4]; int bi = cmb_i[t * 4];
        #pragma unroll
        for (int w = 1; w < 4; ++w) {
            float ov = cmb_v[t * 4 + w];
            int   oi = cmb_i[t * 4 + w];
            if (ov < bv || (ov == bv && oi < bi)) { bv = ov; bi = oi; }
        }
        unsigned long long key =
            ((unsigned long long)__builtin_bit_cast(unsigned, bv + 64.0f) << 32)
            | (unsigned)bi;
        atomicMin(&keys[tb0 + t], key);
    }

    // ---- fused gather: last block (of 32) for this token column does it.
    __syncthreads();     // drains the atomicMins (barrier implies vmcnt 0)
    if (t == 0) {
        __threadfence();                                   // release keys
        unsigned o = atomicAdd(&ctrl[blockIdx.x], 1u);     // done[x]
        sflag = (o == 31u) ? 1 : 0;
    }
    __syncthreads();
    if (sflag) {
        __threadfence();                                   // acquire keys
        if (t < 128) {
            unsigned long long k = keys[tb0 + t];
            int bi  = (int)(unsigned)k;
            float d = __builtin_bit_cast(float, (unsigned)(k >> 32)) - 64.0f;
            sidx[t] = bi;
            atomicAdd(&counts[bi], 1);
            float lt = d + xnorm[tb0 + t];                 // ||x - c||^2
            #pragma unroll
            for (int off = 32; off >= 1; off >>= 1) lt += __shfl_xor(lt, off);
            if ((t & 63) == 0) spart[t >> 6] = lt;
        }
        __syncthreads();
        // wave w gathers tokens w*16..w*16+15: 64 lanes x float4 = full
        // 1KB row per iteration (coalesced; C fp32 is L2/L3-resident).
        #pragma unroll
        for (int r = 0; r < 16; ++r) {
            int tl = wid * 16 + r;
            int e  = sidx[tl];
            float4 q = *(const float4*)&C[(size_t)e * DIM + lane * 4];
            *(float4*)&out[(size_t)(tb0 + tl) * DIM + lane * 4] = q;
        }
        if (t == 0) psum[blockIdx.x] = spart[0] + spart[1];
        __syncthreads();
        if (t == 0) {
            __threadfence();                               // release counts/psum
            unsigned o2 = atomicAdd(&ctrl[64], 1u);        // fin
            sflag = (o2 == 63u) ? 2 : 1;
        }
        __syncthreads();
        // ---- fused finalize: globally last gather block.
        if (sflag == 2) {
            __threadfence();                               // acquire counts/psum
            double local = 0.0;
            #pragma unroll
            for (int i = 0; i < 16; ++i) {
                int e = t + i * 512;
                float p = (float)counts[e] * (1.0f / (float)NTOK);
                local += (double)(p * logf(p + 1e-10f));
            }
            float ls = (t < 64) ? psum[t] : 0.0f;
            #pragma unroll
            for (int off = 32; off >= 1; off >>= 1) {
                local += __shfl_xor(local, off);
                ls    += __shfl_xor(ls, off);
            }
            if (lane == 0) { sdd[wid] = local; sls[wid] = ls; }
            __syncthreads();
            if (t == 0) {
                double ent = 0.0; float ssq = 0.0f;
                #pragma unroll
                for (int w = 0; w < 8; ++w) { ent += sdd[w]; ssq += sls[w]; }
                out[(size_t)NTOK * DIM]     = 1.25f * ssq / (float)((size_t)NTOK * DIM);
                out[(size_t)NTOK * DIM + 1] = expf((float)(-ent));
            }
        }
    }
}

// ---------------------------------------------------------------------------
extern "C" void kernel_launch(void* const* d_in, const int* in_sizes, int n_in,
                              void* d_out, int out_size, void* d_ws, size_t ws_size,
                              hipStream_t stream) {
    const float* X = (const float*)d_in[0];   // [32,256,256] fp32
    const float* C = (const float*)d_in[1];   // [8192,256]   fp32
    float* out = (float*)d_out;

    char* ws = (char*)d_ws;
    size_t o = 0;
    _Float16* Xh = (_Float16*)(ws + o); o += (size_t)NTOK * DIM * 2;
    _Float16* Ch = (_Float16*)(ws + o); o += (size_t)NEMB * DIM * 2;
    float* cnorm = (float*)(ws + o); o += (size_t)NEMB * 4;
    float* xnorm = (float*)(ws + o); o += (size_t)NTOK * 4;
    unsigned long long* keys = (unsigned long long*)(ws + o); o += (size_t)NTOK * 8;
    int* counts  = (int*)(ws + o);   o += (size_t)NEMB * 4;
    float* psum  = (float*)(ws + o); o += (size_t)64 * 4;
    unsigned* ctrl = (unsigned*)(ws + o);     // done[64] + fin

    convert_kernel<<<dim3(NTOK * DIM / 4 / 256, 2), 256, 0, stream>>>(
        X, C, Xh, Ch, cnorm, xnorm, keys, counts, ctrl);
    mfma_argmin_kernel<<<dim3(NTOK / 128, NEMB / 256), 512, 0, stream>>>(
        Xh, Ch, cnorm, keys, C, xnorm, counts, out, psum, ctrl);
}

// Round 8
// 118.785 us; speedup vs baseline: 1.2918x; 1.2918x over previous
//
#include <hip/hip_runtime.h>
#include <math.h>

#define NTOK 8192
#define NEMB 8192
#define DIM  256

typedef _Float16 f16x8 __attribute__((ext_vector_type(8)));   // 4 VGPRs
typedef _Float16 f16x4 __attribute__((ext_vector_type(4)));
typedef float    f32x4 __attribute__((ext_vector_type(4)));

// ---------------------------------------------------------------------------
// Kernel A: cast X and C to fp16 (RNE); fused exact fp32 ||c||^2 and ||x||^2
// (each wave covers exactly one 256-elem row). C-branch blocks x<8 zero
// counts; X-branch blocks x<8 init keys to u64-max; C-branch block x==8
// zeroes the done[64]+fin completion counters (replay-safety for the fused
// last-block gather/finalize).
__global__ __launch_bounds__(256) void convert_kernel(
        const float* __restrict__ X, const float* __restrict__ C,
        _Float16* __restrict__ Xh, _Float16* __restrict__ Ch,
        float* __restrict__ cnorm, float* __restrict__ xnorm,
        unsigned long long* __restrict__ keys, int* __restrict__ counts,
        unsigned* __restrict__ ctrl) {                 // done[64] + fin
    const bool isC = (blockIdx.y != 0);
    if (isC && blockIdx.x < 8) {
        ((int4*)counts)[blockIdx.x * 256 + threadIdx.x] = make_int4(0, 0, 0, 0);
    }
    if (isC && blockIdx.x == 8 && threadIdx.x < 65) {
        ctrl[threadIdx.x] = 0;
    }
    if (!isC && blockIdx.x < 8) {
        int4 ff = make_int4(-1, -1, -1, -1);
        ((int4*)keys)[blockIdx.x * 512 + threadIdx.x * 2]     = ff;
        ((int4*)keys)[blockIdx.x * 512 + threadIdx.x * 2 + 1] = ff;
    }
    const float* src = isC ? C : X;
    _Float16* dst = isC ? Ch : Xh;
    size_t t = (size_t)blockIdx.x * 256 + threadIdx.x;   // one float4 per thread
    float4 x = *(const float4*)&src[t * 4];
    f16x4 h;
    h[0] = (_Float16)x.x; h[1] = (_Float16)x.y;
    h[2] = (_Float16)x.z; h[3] = (_Float16)x.w;
    *(f16x4*)&dst[t * 4] = h;
    float s = x.x * x.x + x.y * x.y + x.z * x.z + x.w * x.w;
    #pragma unroll
    for (int off = 32; off >= 1; off >>= 1) s += __shfl_xor(s, off);
    if ((threadIdx.x & 63) == 0) {
        if (isC) cnorm[t >> 6] = s; else xnorm[t >> 6] = s;
    }
}

// ---------------------------------------------------------------------------
// K32-chunk staging, 256x128 block tile (A=256 codes, B=128 tokens),
// 512 threads / 8 waves of 64x64 each (proven R5 structure, untouched).
// Swizzle s(row) = (row + (row>>2)) & 3 keeps frag ds_read_b128 at 2-way.
__device__ __forceinline__ int swz(int row) { return (row + (row >> 2)) & 3; }

template<int N>
__device__ __forceinline__ void wait_vmcnt() {
    asm volatile("s_waitcnt vmcnt(%0)" :: "n"(N) : "memory");
}

// One K32 chunk: A = 1024 granules, B = 512 granules of 16B. With 512
// threads: 2 A + 1 B = 3 gload_lds/thread — vmcnt(3) relies on this.
__device__ __forceinline__ void stage_k32(
        const _Float16* __restrict__ Ag, const _Float16* __restrict__ Bg,
        _Float16* bufA, _Float16* bufB, int t) {
    #pragma unroll
    for (int c = 0; c < 2; ++c) {
        int gr  = c * 512 + t;
        int row = gr >> 2;
        int kg  = (gr & 3) ^ swz(row);
        __builtin_amdgcn_global_load_lds(
            (const __attribute__((address_space(1))) void*)(Ag + (size_t)row * DIM + kg * 8),
            (__attribute__((address_space(3))) void*)(bufA + (size_t)gr * 8), 16, 0, 0);
    }
    {
        int gr  = t;
        int row = gr >> 2;
        int kg  = (gr & 3) ^ swz(row);
        __builtin_amdgcn_global_load_lds(
            (const __attribute__((address_space(1))) void*)(Bg + (size_t)row * DIM + kg * 8),
            (__attribute__((address_space(3))) void*)(bufB + (size_t)gr * 8), 16, 0, 0);
    }
}

// 64x64 wave tile: 8 ds_read_b128 feed 16 MFMAs; acc = 64 VGPRs so
// 4 waves/SIMD fit (the R5 occupancy win).
__device__ __forceinline__ void compute_k32(
        const _Float16* Abuf, const _Float16* Bbuf, f32x4 (&acc)[4][4],
        int wm, int wn, int lrow, int g) {
    f16x8 af[4], bf_[4];
    #pragma unroll
    for (int i = 0; i < 4; ++i) {
        int row = wm + i * 16 + lrow;
        af[i] = *(const f16x8*)&Abuf[(row * 4 + (g ^ swz(row))) * 8];
    }
    #pragma unroll
    for (int j = 0; j < 4; ++j) {
        int row = wn + j * 16 + lrow;
        bf_[j] = *(const f16x8*)&Bbuf[(row * 4 + (g ^ swz(row))) * 8];
    }
    __builtin_amdgcn_s_setprio(1);
    #pragma unroll
    for (int i = 0; i < 4; ++i)
        #pragma unroll
        for (int j = 0; j < 4; ++j)
            acc[i][j] = __builtin_amdgcn_mfma_f32_16x16x32_f16(
                af[i], bf_[j], acc[i][j], 0, 0, 0);
    __builtin_amdgcn_s_setprio(0);
}

// ---------------------------------------------------------------------------
// Kernel B (FUSED, fence-free): fp16 distance GEMM + argmin (R5 structure,
// unchanged), then the last block per token column gathers/histograms, and
// the globally-last gather block finalizes. R6's regression was the 2048
// __threadfence() calls (each = L2 writeback+invalidate on gfx950, which
// evicted the GEMM's L2-resident staging: MfmaUtil 29->13%, FETCH +4MB).
// Fence-free protocol: ALL cross-block data moves through device-scope
// atomics at the coherence point — writers atomicMin/atomicAdd/atomicExch,
// readers identity-atomics (min with u64max, add 0). Ordering comes from
// __syncthreads (compiler emits s_waitcnt vmcnt(0) before s_barrier, so the
// block's atomics have completed) before the ctrl increment. ctrl re-zeroed
// every launch by convert => replay-safe. Plain stores only for host-read out.
__global__ __launch_bounds__(512, 4) void mfma_argmin_kernel(
        const _Float16* __restrict__ Xh, const _Float16* __restrict__ Ch,
        const float* __restrict__ cnorm,
        unsigned long long* __restrict__ keys,
        const float* __restrict__ C, const float* __restrict__ xnorm,
        int* __restrict__ counts, float* __restrict__ out,
        float* __restrict__ psum, unsigned* __restrict__ ctrl) {
    __shared__ __align__(16) _Float16 lds[36864];   // 72 KB
    _Float16* const ldsB = lds + 24576;             // B ring base (48 KB in)
    __shared__ int   sidx[128];
    __shared__ float spart[8];
    __shared__ double sdd[8];
    __shared__ float  sls[8];
    __shared__ int sflag;

    const int t = threadIdx.x;                      // 0..511
    const int wid = t >> 6, lane = t & 63;
    const int tb0 = blockIdx.x * 128;   // token block
    const int cb0 = blockIdx.y * 256;   // code block
    const int wm = (wid >> 1) * 64;     // wave's code offset (0/64/128/192)
    const int wn = (wid & 1) * 64;      // wave's token offset (0/64)
    const int lrow = lane & 15;
    const int g = lane >> 4;            // quad

    f32x4 acc[4][4];                    // [tm=codes][tn=tokens] = 64 VGPRs
    #pragma unroll
    for (int a = 0; a < 4; ++a)
        #pragma unroll
        for (int b = 0; b < 4; ++b) acc[a][b] = (f32x4)0.0f;

    const _Float16* Ag = Ch + (size_t)cb0 * DIM;   // codes
    const _Float16* Bg = Xh + (size_t)tb0 * DIM;   // tokens

    stage_k32(Ag,      Bg,      lds,        ldsB,        t);  // S(0)
    stage_k32(Ag + 32, Bg + 32, lds + 8192, ldsB + 4096, t);  // S(1)

#define PHASE(P, WAITN)                                                       \
    do {                                                                      \
        wait_vmcnt<WAITN>();                                                  \
        __builtin_amdgcn_s_barrier();                                         \
        __builtin_amdgcn_sched_barrier(0);                                    \
        if ((P) + 2 < 8)                                                      \
            stage_k32(Ag + ((P) + 2) * 32, Bg + ((P) + 2) * 32,               \
                      lds + (((P) + 2) % 3) * 8192,                           \
                      ldsB + (((P) + 2) % 3) * 4096, t);                      \
        compute_k32(lds + ((P) % 3) * 8192, ldsB + ((P) % 3) * 4096,          \
                    acc, wm, wn, lrow, g);                                    \
        __builtin_amdgcn_sched_barrier(0);                                    \
    } while (0)

    PHASE(0, 3); PHASE(1, 3); PHASE(2, 3); PHASE(3, 3);
    PHASE(4, 3); PHASE(5, 3); PHASE(6, 3); PHASE(7, 0);
#undef PHASE

    // ---- epilogue: d = ||c||^2 - 2 c.x ; argmin over this block's 256 codes
    float cn[16];
    #pragma unroll
    for (int tm = 0; tm < 4; ++tm)
        #pragma unroll
        for (int reg = 0; reg < 4; ++reg)
            cn[tm * 4 + reg] = cnorm[cb0 + wm + tm * 16 + g * 4 + reg];

    float* cmb_v = (float*)lds;                    // [128][4]
    int*   cmb_i = (int*)((float*)lds + 512);      // [128][4]

    #pragma unroll
    for (int tn = 0; tn < 4; ++tn) {
        float bv = 1e30f; int bi = 0x7fffffff;
        #pragma unroll
        for (int tm = 0; tm < 4; ++tm) {
            #pragma unroll
            for (int reg = 0; reg < 4; ++reg) {
                float d = fmaf(-2.0f, acc[tm][tn][reg], cn[tm * 4 + reg]);
                int code = cb0 + wm + tm * 16 + g * 4 + reg;  // ascending -> strict <
                if (d < bv) { bv = d; bi = code; }
            }
        }
        #pragma unroll
        for (int off = 16; off <= 32; off <<= 1) {  // reduce over the 4 quads
            float ov = __shfl_xor(bv, off);
            int   oi = __shfl_xor(bi, off);
            if (ov < bv || (ov == bv && oi < bi)) { bv = ov; bi = oi; }
        }
        if (g == 0) {
            int tl = wn + tn * 16 + lrow;           // token-local 0..127
            cmb_v[tl * 4 + (wid >> 1)] = bv;
            cmb_i[tl * 4 + (wid >> 1)] = bi;
        }
    }
    __syncthreads();
    if (t < 128) {
        float bv = cmb_v[t * 4]; int bi = cmb_i[t * 4];
        #pragma unroll
        for (int w = 1; w < 4; ++w) {
            float ov = cmb_v[t * 4 + w];
            int   oi = cmb_i[t * 4 + w];
            if (ov < bv || (ov == bv && oi < bi)) { bv = ov; bi = oi; }
        }
        unsigned long long key =
            ((unsigned long long)__builtin_bit_cast(unsigned, bv + 64.0f) << 32)
            | (unsigned)bi;
        atomicMin(&keys[tb0 + t], key);
    }

    // ---- fused gather: last block (of 32) for this token column does it.
    // __syncthreads => all this block's atomicMins completed (vmcnt 0
    // before s_barrier) => safe to signal without any fence.
    __syncthreads();
    if (t == 0) {
        unsigned o = atomicAdd(&ctrl[blockIdx.x], 1u);     // done[x]
        sflag = (o == 31u) ? 1 : 0;
    }
    __syncthreads();
    if (sflag) {
        if (t < 128) {
            // atomic read at the coherence point (identity-min) — sees all
            // 32 blocks' final keys without any cache fence.
            unsigned long long k =
                atomicMin(&keys[tb0 + t], 0xFFFFFFFFFFFFFFFFull);
            int bi  = (int)(unsigned)k;
            float d = __builtin_bit_cast(float, (unsigned)(k >> 32)) - 64.0f;
            sidx[t] = bi;
            atomicAdd(&counts[bi], 1);
            float lt = d + xnorm[tb0 + t];                 // ||x - c||^2
            #pragma unroll
            for (int off = 32; off >= 1; off >>= 1) lt += __shfl_xor(lt, off);
            if ((t & 63) == 0) spart[t >> 6] = lt;
        }
        __syncthreads();
        // wave w gathers tokens w*16..w*16+15: 64 lanes x float4 = full
        // 1KB row per iteration (coalesced; C fp32 is L2/L3-resident).
        #pragma unroll
        for (int r = 0; r < 16; ++r) {
            int tl = wid * 16 + r;
            int e  = sidx[tl];
            float4 q = *(const float4*)&C[(size_t)e * DIM + lane * 4];
            *(float4*)&out[(size_t)(tb0 + tl) * DIM + lane * 4] = q;
        }
        if (t == 0) atomicExch(&psum[blockIdx.x], spart[0] + spart[1]);
        __syncthreads();   // drain this block's atomics before signaling
        if (t == 0) {
            unsigned o2 = atomicAdd(&ctrl[64], 1u);        // fin
            sflag = (o2 == 63u) ? 2 : 1;
        }
        __syncthreads();
        // ---- fused finalize: globally last gather block. All reads of
        // cross-block data via identity-atomics (coherence point).
        if (sflag == 2) {
            double local = 0.0;
            #pragma unroll
            for (int i = 0; i < 16; ++i) {
                int e = t + i * 512;
                float p = (float)atomicAdd(&counts[e], 0) * (1.0f / (float)NTOK);
                local += (double)(p * logf(p + 1e-10f));
            }
            float ls = (t < 64) ? atomicAdd(&psum[t], 0.0f) : 0.0f;
            #pragma unroll
            for (int off = 32; off >= 1; off >>= 1) {
                local += __shfl_xor(local, off);
                ls    += __shfl_xor(ls, off);
            }
            if (lane == 0) { sdd[wid] = local; sls[wid] = ls; }
            __syncthreads();
            if (t == 0) {
                double ent = 0.0; float ssq = 0.0f;
                #pragma unroll
                for (int w = 0; w < 8; ++w) { ent += sdd[w]; ssq += sls[w]; }
                out[(size_t)NTOK * DIM]     = 1.25f * ssq / (float)((size_t)NTOK * DIM);
                out[(size_t)NTOK * DIM + 1] = expf((float)(-ent));
            }
        }
    }
}

// ---------------------------------------------------------------------------
extern "C" void kernel_launch(void* const* d_in, const int* in_sizes, int n_in,
                              void* d_out, int out_size, void* d_ws, size_t ws_size,
                              hipStream_t stream) {
    const float* X = (const float*)d_in[0];   // [32,256,256] fp32
    const float* C = (const float*)d_in[1];   // [8192,256]   fp32
    float* out = (float*)d_out;

    char* ws = (char*)d_ws;
    size_t o = 0;
    _Float16* Xh = (_Float16*)(ws + o); o += (size_t)NTOK * DIM * 2;
    _Float16* Ch = (_Float16*)(ws + o); o += (size_t)NEMB * DIM * 2;
    float* cnorm = (float*)(ws + o); o += (size_t)NEMB * 4;
    float* xnorm = (float*)(ws + o); o += (size_t)NTOK * 4;
    unsigned long long* keys = (unsigned long long*)(ws + o); o += (size_t)NTOK * 8;
    int* counts  = (int*)(ws + o);   o += (size_t)NEMB * 4;
    float* psum  = (float*)(ws + o); o += (size_t)64 * 4;
    unsigned* ctrl = (unsigned*)(ws + o);     // done[64] + fin

    convert_kernel<<<dim3(NTOK * DIM / 4 / 256, 2), 256, 0, stream>>>(
        X, C, Xh, Ch, cnorm, xnorm, keys, counts, ctrl);
    mfma_argmin_kernel<<<dim3(NTOK / 128, NEMB / 256), 512, 0, stream>>>(
        Xh, Ch, cnorm, keys, C, xnorm, counts, out, psum, ctrl);
}